// Round 1
// baseline (3000.307 us; speedup 1.0000x reference)
//
#include <hip/hip_runtime.h>
#include <math.h>
#include <stdint.h>

#define B_ 8
#define N_ 2048
#define K_ 20
#define EPSV 1e-5f
#define SLOPEV 0.2f

static __device__ __forceinline__ float leakyf(float v){ return v >= 0.f ? v : SLOPEV*v; }

// ---------------- transpose input (B,3,N) -> (B,N,3) ----------------
__global__ void k_transpose_in(const float* __restrict__ x, float* __restrict__ xt){
  int id = blockIdx.x*256 + threadIdx.x;
  if (id >= B_*N_) return;
  int b = id / N_, n = id % N_;
  #pragma unroll
  for (int c = 0; c < 3; ++c)
    xt[((size_t)b*N_+n)*3 + c] = x[((size_t)b*3+c)*N_ + n];
}

// ---------------- Wa[o][c] = W[o][c]; Wd[o][c] = W[o][C+c]-W[o][c] ----------------
__global__ void k_prep_w(const float* __restrict__ W, float* __restrict__ Wa,
                         float* __restrict__ Wd, int O, int C){
  int id = blockIdx.x*256 + threadIdx.x;
  if (id >= O*C) return;
  int o = id / C, c = id % C;
  float a = W[(size_t)o*2*C + c];
  float d = W[(size_t)o*2*C + C + c];
  Wa[id] = a; Wd[id] = d - a;
}

// ---------------- xx[b*N+n] = sum_c X[(b*N+n)*ld + c]^2 ----------------
__global__ void k_sqnorm(const float* __restrict__ X, int ld, int C, float* __restrict__ xx){
  int id = blockIdx.x*256 + threadIdx.x;
  if (id >= B_*N_) return;
  const float* p = X + (size_t)id*ld;
  float s = 0.f;
  for (int c = 0; c < C; ++c) s = fmaf(p[c], p[c], s);
  xx[id] = s;
}

// ---------------- generic NT GEMM: C[m][n] = sum_k A[m][k]*B[n][k] ----------------
// MODE 0: plain store.  MODE 1: pd store: 2*acc - xx[m] - xx[n]
#define BM 64
#define BN 64
#define BKT 16

template<int MODE>
__global__ __launch_bounds__(256)
void k_gemm_nt(const float* __restrict__ A, int lda, long sA,
               const float* __restrict__ Bm, int ldb, long sB,
               float* __restrict__ Cm, int ldc, long sC,
               int K, const float* __restrict__ xx, long sX){
  __shared__ float As[BKT][BM+4];
  __shared__ float Bs[BKT][BN+4];
  const int z = blockIdx.z;
  const float* Ab = A + (size_t)z*sA;
  const float* Bb = Bm + (size_t)z*sB;
  float* Cb = Cm + (size_t)z*sC;
  const int m0 = blockIdx.x*BM, n0 = blockIdx.y*BN;
  const int tid = threadIdx.x;
  const int tm = tid >> 4, tn = tid & 15;
  const int lm = tid >> 2, lk = (tid & 3)*4;
  float acc[4][4] = {};
  for (int k0 = 0; k0 < K; k0 += BKT){
    #pragma unroll
    for (int i = 0; i < 4; ++i){
      int kk = lk + i;
      As[kk][lm] = (k0+kk < K) ? Ab[(size_t)(m0+lm)*lda + k0+kk] : 0.f;
      Bs[kk][lm] = (k0+kk < K) ? Bb[(size_t)(n0+lm)*ldb + k0+kk] : 0.f;
    }
    __syncthreads();
    #pragma unroll
    for (int kk = 0; kk < BKT; ++kk){
      float a4[4], b4[4];
      *(float4*)a4 = *(const float4*)&As[kk][tm*4];
      *(float4*)b4 = *(const float4*)&Bs[kk][tn*4];
      #pragma unroll
      for (int i = 0; i < 4; ++i)
        #pragma unroll
        for (int j = 0; j < 4; ++j)
          acc[i][j] = fmaf(a4[i], b4[j], acc[i][j]);
    }
    __syncthreads();
  }
  if (MODE == 0){
    #pragma unroll
    for (int i = 0; i < 4; ++i){
      int m = m0 + tm*4 + i;
      #pragma unroll
      for (int j = 0; j < 4; ++j)
        Cb[(size_t)m*ldc + n0 + tn*4 + j] = acc[i][j];
    }
  } else {
    const float* xb = xx + (size_t)z*sX;
    #pragma unroll
    for (int i = 0; i < 4; ++i){
      int m = m0 + tm*4 + i;
      float xm = xb[m];
      #pragma unroll
      for (int j = 0; j < 4; ++j){
        int n = n0 + tn*4 + j;
        Cb[(size_t)m*ldc + n] = 2.f*acc[i][j] - xm - xb[n];
      }
    }
  }
}

// ---------------- top-20 per row of pd (chunk of 2 batches). one wave per row ----------------
__global__ __launch_bounds__(256)
void k_topk(const float* __restrict__ pd, int b0, int* __restrict__ idx){
  __shared__ float dist[4][N_];
  const int w = threadIdx.x >> 6, lane = threadIdx.x & 63;
  const int row = blockIdx.x*4 + w;  // row within chunk
  const float* prow = pd + (size_t)row * N_;
  float* d = dist[w];
  for (int t = lane; t < N_; t += 64) d[t] = prow[t];
  const int gb = b0 + row / N_;
  const int n = row % N_;
  int* out = idx + ((size_t)gb*N_ + n)*K_;
  for (int t = 0; t < K_; ++t){
    float best = -INFINITY; int bi = N_;
    for (int j = lane; j < N_; j += 64){
      float v = d[j];
      if (v > best || (v == best && j < bi)){ best = v; bi = j; }
    }
    #pragma unroll
    for (int off = 32; off; off >>= 1){
      float ov = __shfl_xor(best, off);
      int oi = __shfl_xor(bi, off);
      if (ov > best || (ov == best && oi < bi)){ best = ov; bi = oi; }
    }
    if (lane == 0){ out[t] = bi; d[bi] = -INFINITY; }
  }
}

// ---------------- gather + max over k + BN stats; writes pre-BN max into xc slice ----------------
__global__ __launch_bounds__(256)
void k_edge_assemble(const float* __restrict__ u, const float* __restrict__ v,
                     const int* __restrict__ idx, float* __restrict__ xc,
                     int O, int c0, double* __restrict__ ssum, double* __restrict__ ssq){
  const int tid = threadIdx.x;
  const int npar = 256 / O;            // O in {64,128,256}
  const int o = tid % O;
  const int slot = tid / O;
  const int nb = N_/64;
  const int b = blockIdx.x / nb, tile = blockIdx.x % nb;
  float lsum = 0.f, lsq = 0.f;
  for (int i = slot; i < 64; i += npar){
    int n = tile*64 + i;
    const float vv = v[((size_t)b*N_+n)*O + o];
    const int* ip = idx + ((size_t)b*N_+n)*K_;
    float m = -INFINITY;
    #pragma unroll
    for (int kk = 0; kk < K_; ++kk){
      int j = ip[kk];
      float h = u[((size_t)b*N_+j)*O + o] + vv;
      m = fmaxf(m, h);
      lsum += h;
      lsq = fmaf(h, h, lsq);
    }
    xc[((size_t)b*N_+n)*512 + c0 + o] = m;
  }
  atomicAdd(&ssum[o], (double)lsum);
  atomicAdd(&ssq[o], (double)lsq);
}

// ---------------- BN scale/shift from stats ----------------
__global__ void k_bn_finalize(const double* __restrict__ ssum, const double* __restrict__ ssq,
                              const float* __restrict__ g, const float* __restrict__ bb,
                              float* __restrict__ sc, float* __restrict__ sh, int O, double cnt){
  int o = threadIdx.x;
  if (o >= O) return;
  double mean = ssum[o] / cnt;
  double var = ssq[o] / cnt - mean*mean;
  if (var < 0.0) var = 0.0;
  float inv = rsqrtf((float)var + EPSV);
  float s = g[o] * inv;
  sc[o] = s;
  sh[o] = bb[o] - (float)mean * s;
}

// ---------------- in-place BN + leaky on xc slice ----------------
__global__ void k_bn_apply(float* __restrict__ xc, int O, int c0,
                           const float* __restrict__ sc, const float* __restrict__ sh){
  int id = blockIdx.x*256 + threadIdx.x;
  if (id >= B_*N_*O) return;
  int o = id % O;
  size_t pn = (size_t)(id / O);
  float* p = &xc[pn*512 + c0 + o];
  float val = fmaf(*p, sc[o], sh[o]);
  *p = leakyf(val);
}

// ---------------- per-channel stats over h5 (B,N,512) ----------------
__global__ void k_h5_stats(const float* __restrict__ h5, double* __restrict__ ssum, double* __restrict__ ssq){
  const int o = threadIdx.x;  // 512
  const int nb = N_/64;
  const int b = blockIdx.x / nb, tile = blockIdx.x % nb;
  float ls = 0.f, lq = 0.f;
  for (int i = 0; i < 64; ++i){
    float v = h5[((size_t)b*N_ + tile*64 + i)*512 + o];
    ls += v;
    lq = fmaf(v, v, lq);
  }
  atomicAdd(&ssum[o], (double)ls);
  atomicAdd(&ssq[o], (double)lq);
}

// ---------------- BN+leaky + max/mean over N -> out (B,1024) ----------------
__global__ void k_final(const float* __restrict__ h5, const float* __restrict__ sc,
                        const float* __restrict__ sh, float* __restrict__ out){
  const int o = threadIdx.x;  // 512
  const int b = blockIdx.x;
  const float s = sc[o], t = sh[o];
  float mx = -INFINITY, sm = 0.f;
  for (int n = 0; n < N_; ++n){
    float v = leakyf(fmaf(h5[((size_t)b*N_+n)*512 + o], s, t));
    mx = fmaxf(mx, v);
    sm += v;
  }
  out[(size_t)b*1024 + o] = mx;
  out[(size_t)b*1024 + 512 + o] = sm * (1.f/N_);
}

extern "C" void kernel_launch(void* const* d_in, const int* in_sizes, int n_in,
                              void* d_out, int out_size, void* d_ws, size_t ws_size,
                              hipStream_t stream){
  const float* x  = (const float*)d_in[0];
  const float* W1 = (const float*)d_in[2];
  const float* g1 = (const float*)d_in[3];
  const float* b1 = (const float*)d_in[4];
  const float* W2 = (const float*)d_in[5];
  const float* g2 = (const float*)d_in[6];
  const float* b2 = (const float*)d_in[7];
  const float* W3 = (const float*)d_in[8];
  const float* g3 = (const float*)d_in[9];
  const float* b3 = (const float*)d_in[10];
  const float* W4 = (const float*)d_in[11];
  const float* g4 = (const float*)d_in[12];
  const float* b4 = (const float*)d_in[13];
  const float* W5 = (const float*)d_in[14];
  const float* g5 = (const float*)d_in[15];
  const float* b5 = (const float*)d_in[16];
  float* out = (float*)d_out;

  // workspace bump allocation (floats); total ~103 MB
  float* w = (float*)d_ws;
  float* xc  = w; w += (size_t)B_*N_*512;       // 8.39M  : concat output (b,n,c) point-major
  float* h5  = w; w += (size_t)B_*N_*512;       // 8.39M  : head GEMM output
  float* R   = w; w += (size_t)2*N_*N_;         // 8.39M  : pd chunk (2 batches) OR u_t+v_t
  float* x0t = w; w += (size_t)B_*N_*4;         // input transposed (b,n,3), padded
  float* xx  = w; w += (size_t)B_*N_;
  float* Wa  = w; w += 256*128;
  float* Wd  = w; w += 256*128;
  float* sc  = w; w += 512;
  float* sh  = w; w += 512;
  double* ssum = (double*)w; w += 1024;         // 512 doubles
  double* ssq  = (double*)w; w += 1024;
  int* idxp  = (int*)w; w += (size_t)B_*N_*K_;
  (void)ws_size; (void)in_sizes; (void)n_in; (void)out_size;

  float* u_t = R;
  float* v_t = R + (size_t)B_*N_*256;

  k_transpose_in<<<dim3((B_*N_)/256), dim3(256), 0, stream>>>(x, x0t);

  struct Cfg { const float* Xin; int lda; int Cin; const float* W; const float* g; const float* bb; int O; int c0; };
  Cfg cfgs[4] = {
    { x0t,      3,   3,   W1, g1, b1, 64,  0   },
    { xc + 0,   512, 64,  W2, g2, b2, 64,  64  },
    { xc + 64,  512, 64,  W3, g3, b3, 128, 128 },
    { xc + 128, 512, 128, W4, g4, b4, 256, 256 },
  };

  for (int e = 0; e < 4; ++e){
    Cfg c = cfgs[e];
    k_prep_w<<<dim3((c.O*c.Cin + 255)/256), dim3(256), 0, stream>>>(c.W, Wa, Wd, c.O, c.Cin);
    k_sqnorm<<<dim3((B_*N_)/256), dim3(256), 0, stream>>>(c.Xin, c.lda, c.Cin, xx);
    // pairwise distances + top-k, 2 batches at a time through R
    for (int ch = 0; ch < 4; ++ch){
      int b0 = ch*2;
      k_gemm_nt<1><<<dim3(N_/BM, N_/BN, 2), dim3(256), 0, stream>>>(
        c.Xin + (size_t)b0*N_*c.lda, c.lda, (long)N_*c.lda,
        c.Xin + (size_t)b0*N_*c.lda, c.lda, (long)N_*c.lda,
        R, N_, (long)N_*N_, c.Cin, xx + b0*N_, (long)N_);
      k_topk<<<dim3((2*N_)/4), dim3(256), 0, stream>>>(R, b0, idxp);
    }
    // u = x . Wa^T, v = x . Wd^T  (point-major outputs, reuse R)
    k_gemm_nt<0><<<dim3(N_/BM, c.O/BN, B_), dim3(256), 0, stream>>>(
      c.Xin, c.lda, (long)N_*c.lda, Wa, c.Cin, 0L,
      u_t, c.O, (long)N_*c.O, c.Cin, nullptr, 0L);
    k_gemm_nt<0><<<dim3(N_/BM, c.O/BN, B_), dim3(256), 0, stream>>>(
      c.Xin, c.lda, (long)N_*c.lda, Wd, c.Cin, 0L,
      v_t, c.O, (long)N_*c.O, c.Cin, nullptr, 0L);
    hipMemsetAsync(ssum, 0, 2*512*sizeof(double), stream);
    k_edge_assemble<<<dim3(B_*(N_/64)), dim3(256), 0, stream>>>(u_t, v_t, idxp, xc, c.O, c.c0, ssum, ssq);
    k_bn_finalize<<<dim3(1), dim3(512), 0, stream>>>(ssum, ssq, c.g, c.bb, sc, sh, c.O, (double)B_*N_*K_);
    k_bn_apply<<<dim3((B_*N_*c.O)/256), dim3(256), 0, stream>>>(xc, c.O, c.c0, sc, sh);
  }

  // head: h5 = xc . W5^T, BN stats, finalize, pool
  k_gemm_nt<0><<<dim3(N_/BM, 512/BN, B_), dim3(256), 0, stream>>>(
    xc, 512, (long)N_*512, W5, 512, 0L, h5, 512, (long)N_*512, 512, nullptr, 0L);
  hipMemsetAsync(ssum, 0, 2*512*sizeof(double), stream);
  k_h5_stats<<<dim3(B_*(N_/64)), dim3(512), 0, stream>>>(h5, ssum, ssq);
  k_bn_finalize<<<dim3(1), dim3(512), 0, stream>>>(ssum, ssq, g5, b5, sc, sh, 512, (double)B_*N_);
  k_final<<<dim3(B_), dim3(512), 0, stream>>>(h5, sc, sh, out);
}

// Round 2
// 2505.900 us; speedup vs baseline: 1.1973x; 1.1973x over previous
//
#include <hip/hip_runtime.h>
#include <math.h>
#include <stdint.h>

#define B_ 8
#define N_ 2048
#define K_ 20
#define EPSV 1e-5f
#define SLOPEV 0.2f

static __device__ __forceinline__ float leakyf(float v){ return v >= 0.f ? v : SLOPEV*v; }

// ---------------- transpose input (B,3,N) -> (B,N,8) zero-padded ----------------
__global__ void k_transpose_in(const float* __restrict__ x, float* __restrict__ xt){
  int id = blockIdx.x*256 + threadIdx.x;
  if (id >= B_*N_) return;
  int b = id / N_, n = id % N_;
  float4 z0, z1 = {0.f,0.f,0.f,0.f};
  z0.x = x[((size_t)b*3+0)*N_ + n];
  z0.y = x[((size_t)b*3+1)*N_ + n];
  z0.z = x[((size_t)b*3+2)*N_ + n];
  z0.w = 0.f;
  ((float4*)&xt[(size_t)id*8])[0] = z0;
  ((float4*)&xt[(size_t)id*8])[1] = z1;
}

// ---------------- Wa[o][c] = W[o][c]; Wd[o][c] = W[o][C+c]-W[o][c] ----------------
__global__ void k_prep_w(const float* __restrict__ W, float* __restrict__ Wa,
                         float* __restrict__ Wd, int O, int C){
  int id = blockIdx.x*256 + threadIdx.x;
  if (id >= O*C) return;
  int o = id / C, c = id % C;
  float a = W[(size_t)o*2*C + c];
  float d = W[(size_t)o*2*C + C + c];
  Wa[id] = a; Wd[id] = d - a;
}

// ---------------- xx[b*N+n] = sum_c X[(b*N+n)*ld + c]^2 ----------------
__global__ void k_sqnorm(const float* __restrict__ X, int ld, int C, float* __restrict__ xx){
  int id = blockIdx.x*256 + threadIdx.x;
  if (id >= B_*N_) return;
  const float* p = X + (size_t)id*ld;
  float s = 0.f;
  for (int c = 0; c < C; ++c) s = fmaf(p[c], p[c], s);
  xx[id] = s;
}

// ---------------- small NT GEMM (64x64 tile) kept for O=64 u/v GEMMs ----------------
#define BM 64
#define BN 64
#define BKT 16

template<int MODE>
__global__ __launch_bounds__(256)
void k_gemm_nt(const float* __restrict__ A, int lda, long sA,
               const float* __restrict__ Bm, int ldb, long sB,
               float* __restrict__ Cm, int ldc, long sC,
               int K, const float* __restrict__ xx, long sX){
  __shared__ float As[BKT][BM+4];
  __shared__ float Bs[BKT][BN+4];
  const int z = blockIdx.z;
  const float* Ab = A + (size_t)z*sA;
  const float* Bb = Bm + (size_t)z*sB;
  float* Cb = Cm + (size_t)z*sC;
  const int m0 = blockIdx.x*BM, n0 = blockIdx.y*BN;
  const int tid = threadIdx.x;
  const int tm = tid >> 4, tn = tid & 15;
  const int lm = tid >> 2, lk = (tid & 3)*4;
  float acc[4][4] = {};
  for (int k0 = 0; k0 < K; k0 += BKT){
    #pragma unroll
    for (int i = 0; i < 4; ++i){
      int kk = lk + i;
      As[kk][lm] = (k0+kk < K) ? Ab[(size_t)(m0+lm)*lda + k0+kk] : 0.f;
      Bs[kk][lm] = (k0+kk < K) ? Bb[(size_t)(n0+lm)*ldb + k0+kk] : 0.f;
    }
    __syncthreads();
    #pragma unroll
    for (int kk = 0; kk < BKT; ++kk){
      float a4[4], b4[4];
      *(float4*)a4 = *(const float4*)&As[kk][tm*4];
      *(float4*)b4 = *(const float4*)&Bs[kk][tn*4];
      #pragma unroll
      for (int i = 0; i < 4; ++i)
        #pragma unroll
        for (int j = 0; j < 4; ++j)
          acc[i][j] = fmaf(a4[i], b4[j], acc[i][j]);
    }
    __syncthreads();
  }
  #pragma unroll
  for (int i = 0; i < 4; ++i){
    int m = m0 + tm*4 + i;
    #pragma unroll
    for (int j = 0; j < 4; ++j)
      Cb[(size_t)m*ldc + n0 + tn*4 + j] = acc[i][j];
  }
  (void)xx; (void)sX;
}

// ---------------- big NT GEMM: 128x128 tile, 8x8 per thread, BK=8 ----------------
// C[m][n] = sum_k A[m][k]*B[n][k].  MODE 0: plain. MODE 1: 2*acc - xx[m] - xx[n]
#define GBM 128
#define GBN 128
#define GBK 8

template<int MODE>
__global__ __launch_bounds__(256)
void k_gemm128(const float* __restrict__ A, int lda, long sA,
               const float* __restrict__ Bm, int ldb, long sB,
               float* __restrict__ Cm, int ldc, long sC,
               int K, const float* __restrict__ xx, long sX){
  __shared__ float As[GBK][GBM];
  __shared__ float Bs[GBK][GBN];
  const int z = blockIdx.z;
  const float* Ab = A + (size_t)z*sA;
  const float* Bb = Bm + (size_t)z*sB;
  float* Cb = Cm + (size_t)z*sC;
  const int m0 = blockIdx.x*GBM, n0 = blockIdx.y*GBN;
  const int t = threadIdx.x;
  const int tm = t >> 4, tn = t & 15;     // 16x16 thread grid
  const int sr = t >> 1;                  // staging row 0..127
  const int sk = (t & 1) * 4;             // staging col 0 or 4
  float acc[8][8] = {};
  for (int k0 = 0; k0 < K; k0 += GBK){
    float4 av = *(const float4*)&Ab[(size_t)(m0+sr)*lda + k0 + sk];
    float4 bv = *(const float4*)&Bb[(size_t)(n0+sr)*ldb + k0 + sk];
    __syncthreads();   // previous tile fully consumed
    As[sk+0][sr]=av.x; As[sk+1][sr]=av.y; As[sk+2][sr]=av.z; As[sk+3][sr]=av.w;
    Bs[sk+0][sr]=bv.x; Bs[sk+1][sr]=bv.y; Bs[sk+2][sr]=bv.z; Bs[sk+3][sr]=bv.w;
    __syncthreads();
    #pragma unroll
    for (int kk = 0; kk < GBK; ++kk){
      float a[8], b[8];
      *(float4*)&a[0] = *(const float4*)&As[kk][tm*4];
      *(float4*)&a[4] = *(const float4*)&As[kk][64 + tm*4];
      *(float4*)&b[0] = *(const float4*)&Bs[kk][tn*4];
      *(float4*)&b[4] = *(const float4*)&Bs[kk][64 + tn*4];
      #pragma unroll
      for (int i = 0; i < 8; ++i)
        #pragma unroll
        for (int j = 0; j < 8; ++j)
          acc[i][j] = fmaf(a[i], b[j], acc[i][j]);
    }
  }
  float xn[8];
  if (MODE == 1){
    const float* xb = xx + (size_t)z*sX;
    #pragma unroll
    for (int j = 0; j < 8; ++j)
      xn[j] = xb[n0 + ((j<4) ? (tn*4+j) : (64+tn*4+j-4))];
  }
  #pragma unroll
  for (int i = 0; i < 8; ++i){
    int m = m0 + ((i<4) ? (tm*4+i) : (64+tm*4+i-4));
    float4 v0, v1;
    if (MODE == 1){
      const float* xb = xx + (size_t)z*sX;
      float xm = xb[m];
      v0.x = 2.f*acc[i][0]-xm-xn[0]; v0.y = 2.f*acc[i][1]-xm-xn[1];
      v0.z = 2.f*acc[i][2]-xm-xn[2]; v0.w = 2.f*acc[i][3]-xm-xn[3];
      v1.x = 2.f*acc[i][4]-xm-xn[4]; v1.y = 2.f*acc[i][5]-xm-xn[5];
      v1.z = 2.f*acc[i][6]-xm-xn[6]; v1.w = 2.f*acc[i][7]-xm-xn[7];
    } else {
      v0.x = acc[i][0]; v0.y = acc[i][1]; v0.z = acc[i][2]; v0.w = acc[i][3];
      v1.x = acc[i][4]; v1.y = acc[i][5]; v1.z = acc[i][6]; v1.w = acc[i][7];
    }
    *(float4*)&Cb[(size_t)m*ldc + n0 + tn*4]      = v0;
    *(float4*)&Cb[(size_t)m*ldc + n0 + 64 + tn*4] = v1;
  }
}

// ---------------- top-20 per row of pd (chunk of 2 batches). one wave per row ----------------
__global__ __launch_bounds__(256)
void k_topk(const float* __restrict__ pd, int b0, int* __restrict__ idx){
  __shared__ float dist[4][N_];
  const int w = threadIdx.x >> 6, lane = threadIdx.x & 63;
  const int row = blockIdx.x*4 + w;  // row within chunk
  const float* prow = pd + (size_t)row * N_;
  float* d = dist[w];
  for (int t = lane; t < N_; t += 64) d[t] = prow[t];
  const int gb = b0 + row / N_;
  const int n = row % N_;
  int* out = idx + ((size_t)gb*N_ + n)*K_;
  for (int t = 0; t < K_; ++t){
    float best = -INFINITY; int bi = N_;
    for (int j = lane; j < N_; j += 64){
      float v = d[j];
      if (v > best || (v == best && j < bi)){ best = v; bi = j; }
    }
    #pragma unroll
    for (int off = 32; off; off >>= 1){
      float ov = __shfl_xor(best, off);
      int oi = __shfl_xor(bi, off);
      if (ov > best || (ov == best && oi < bi)){ best = ov; bi = oi; }
    }
    if (lane == 0){ out[t] = bi; d[bi] = -INFINITY; }
  }
}

// ---------------- gather + max over k + BN stats (fp32 atomics) ----------------
__global__ __launch_bounds__(256)
void k_edge_assemble(const float* __restrict__ u, const float* __restrict__ v,
                     const int* __restrict__ idx, float* __restrict__ xc,
                     int O, int c0, float* __restrict__ ssum, float* __restrict__ ssq){
  const int tid = threadIdx.x;
  const int npar = 256 / O;            // O in {64,128,256}
  const int o = tid % O;
  const int slot = tid / O;
  const int nb = N_/64;
  const int b = blockIdx.x / nb, tile = blockIdx.x % nb;
  float lsum = 0.f, lsq = 0.f;
  for (int i = slot; i < 64; i += npar){
    int n = tile*64 + i;
    const float vv = v[((size_t)b*N_+n)*O + o];
    const int* ip = idx + ((size_t)b*N_+n)*K_;
    float m = -INFINITY;
    #pragma unroll
    for (int kk = 0; kk < K_; ++kk){
      int j = ip[kk];
      float h = u[((size_t)b*N_+j)*O + o] + vv;
      m = fmaxf(m, h);
      lsum += h;
      lsq = fmaf(h, h, lsq);
    }
    xc[((size_t)b*N_+n)*512 + c0 + o] = m;
  }
  atomicAdd(&ssum[o], lsum);
  atomicAdd(&ssq[o], lsq);
}

// ---------------- BN scale/shift from stats ----------------
__global__ void k_bn_finalize(const float* __restrict__ ssum, const float* __restrict__ ssq,
                              const float* __restrict__ g, const float* __restrict__ bb,
                              float* __restrict__ sc, float* __restrict__ sh, int O, double cnt){
  int o = threadIdx.x;
  if (o >= O) return;
  double mean = (double)ssum[o] / cnt;
  double var = (double)ssq[o] / cnt - mean*mean;
  if (var < 0.0) var = 0.0;
  float inv = rsqrtf((float)var + EPSV);
  float s = g[o] * inv;
  sc[o] = s;
  sh[o] = bb[o] - (float)mean * s;
}

// ---------------- in-place BN + leaky on xc slice ----------------
__global__ void k_bn_apply(float* __restrict__ xc, int O, int c0,
                           const float* __restrict__ sc, const float* __restrict__ sh){
  int id = blockIdx.x*256 + threadIdx.x;
  if (id >= B_*N_*O) return;
  int o = id % O;
  size_t pn = (size_t)(id / O);
  float* p = &xc[pn*512 + c0 + o];
  float val = fmaf(*p, sc[o], sh[o]);
  *p = leakyf(val);
}

// ---------------- per-channel stats over h5 (B,N,512) ----------------
__global__ void k_h5_stats(const float* __restrict__ h5, float* __restrict__ ssum, float* __restrict__ ssq){
  const int o = threadIdx.x;  // 512
  const int nb = N_/64;
  const int b = blockIdx.x / nb, tile = blockIdx.x % nb;
  float ls = 0.f, lq = 0.f;
  for (int i = 0; i < 64; ++i){
    float v = h5[((size_t)b*N_ + tile*64 + i)*512 + o];
    ls += v;
    lq = fmaf(v, v, lq);
  }
  atomicAdd(&ssum[o], ls);
  atomicAdd(&ssq[o], lq);
}

// ---------------- BN+leaky + max/mean over N, two-stage ----------------
__global__ void k_final_partial(const float* __restrict__ h5, const float* __restrict__ sc,
                                const float* __restrict__ sh, float* __restrict__ pmax,
                                float* __restrict__ psum){
  const int o = threadIdx.x;  // 512
  const int b = blockIdx.x >> 4, c = blockIdx.x & 15;
  const float s = sc[o], t = sh[o];
  float mx = -INFINITY, sm = 0.f;
  for (int i = 0; i < 128; ++i){
    int n = c*128 + i;
    float v = leakyf(fmaf(h5[((size_t)b*N_+n)*512 + o], s, t));
    mx = fmaxf(mx, v);
    sm += v;
  }
  pmax[(size_t)blockIdx.x*512 + o] = mx;
  psum[(size_t)blockIdx.x*512 + o] = sm;
}

__global__ void k_final_combine(const float* __restrict__ pmax, const float* __restrict__ psum,
                                float* __restrict__ out){
  const int o = threadIdx.x;  // 512
  const int b = blockIdx.x;
  float mx = -INFINITY, sm = 0.f;
  for (int c = 0; c < 16; ++c){
    mx = fmaxf(mx, pmax[((size_t)b*16+c)*512 + o]);
    sm += psum[((size_t)b*16+c)*512 + o];
  }
  out[(size_t)b*1024 + o] = mx;
  out[(size_t)b*1024 + 512 + o] = sm * (1.f/N_);
}

extern "C" void kernel_launch(void* const* d_in, const int* in_sizes, int n_in,
                              void* d_out, int out_size, void* d_ws, size_t ws_size,
                              hipStream_t stream){
  const float* x  = (const float*)d_in[0];
  const float* W1 = (const float*)d_in[2];
  const float* g1 = (const float*)d_in[3];
  const float* b1 = (const float*)d_in[4];
  const float* W2 = (const float*)d_in[5];
  const float* g2 = (const float*)d_in[6];
  const float* b2 = (const float*)d_in[7];
  const float* W3 = (const float*)d_in[8];
  const float* g3 = (const float*)d_in[9];
  const float* b3 = (const float*)d_in[10];
  const float* W4 = (const float*)d_in[11];
  const float* g4 = (const float*)d_in[12];
  const float* b4 = (const float*)d_in[13];
  const float* W5 = (const float*)d_in[14];
  const float* g5 = (const float*)d_in[15];
  const float* b5 = (const float*)d_in[16];
  float* out = (float*)d_out;

  // workspace bump allocation (floats); ~102.5 MB total
  float* w = (float*)d_ws;
  float* xc  = w; w += (size_t)B_*N_*512;       // concat output (b,n,c) point-major
  float* h5  = w; w += (size_t)B_*N_*512;       // head GEMM output (x0t aliases its head)
  float* R   = w; w += (size_t)2*N_*N_;         // pd chunk (2 batches) OR u_t+v_t OR pmax/psum
  float* xx  = w; w += (size_t)B_*N_;
  float* Wa  = w; w += 256*128;
  float* Wd  = w; w += 256*128;
  float* sc  = w; w += 512;
  float* sh  = w; w += 512;
  float* ssum = w; w += 512;
  float* ssq  = w; w += 512;
  int* idxp  = (int*)w; w += (size_t)B_*N_*K_;
  (void)ws_size; (void)in_sizes; (void)n_in; (void)out_size;

  float* x0t = h5;                   // (B,N,8) zero-padded; dead before h5 is written
  float* u_t = R;
  float* v_t = R + (size_t)B_*N_*256;
  float* pmax = R;                   // used only after R's other uses are dead
  float* psum = R + 128*512;

  k_transpose_in<<<dim3((B_*N_)/256), dim3(256), 0, stream>>>(x, x0t);

  struct Cfg { const float* Xin; int lda; int Cin; int Kpd; const float* W; const float* g; const float* bb; int O; int c0; };
  Cfg cfgs[4] = {
    { x0t,      8,   3,   8,   W1, g1, b1, 64,  0   },
    { xc + 0,   512, 64,  64,  W2, g2, b2, 64,  64  },
    { xc + 64,  512, 64,  64,  W3, g3, b3, 128, 128 },
    { xc + 128, 512, 128, 128, W4, g4, b4, 256, 256 },
  };

  for (int e = 0; e < 4; ++e){
    Cfg c = cfgs[e];
    k_prep_w<<<dim3((c.O*c.Cin + 255)/256), dim3(256), 0, stream>>>(c.W, Wa, Wd, c.O, c.Cin);
    k_sqnorm<<<dim3((B_*N_)/256), dim3(256), 0, stream>>>(c.Xin, c.lda, c.Cin, xx);
    // pairwise distances + top-k, 2 batches at a time through R
    for (int ch = 0; ch < 4; ++ch){
      int b0 = ch*2;
      k_gemm128<1><<<dim3(N_/GBM, N_/GBN, 2), dim3(256), 0, stream>>>(
        c.Xin + (size_t)b0*N_*c.lda, c.lda, (long)N_*c.lda,
        c.Xin + (size_t)b0*N_*c.lda, c.lda, (long)N_*c.lda,
        R, N_, (long)N_*N_, c.Kpd, xx + b0*N_, (long)N_);
      k_topk<<<dim3((2*N_)/4), dim3(256), 0, stream>>>(R, b0, idxp);
    }
    // u = x . Wa^T, v = x . Wd^T  (point-major outputs, reuse R)
    if (c.O >= 128){
      k_gemm128<0><<<dim3(N_/GBM, c.O/GBN, B_), dim3(256), 0, stream>>>(
        c.Xin, c.lda, (long)N_*c.lda, Wa, c.Cin, 0L,
        u_t, c.O, (long)N_*c.O, c.Cin, nullptr, 0L);
      k_gemm128<0><<<dim3(N_/GBM, c.O/GBN, B_), dim3(256), 0, stream>>>(
        c.Xin, c.lda, (long)N_*c.lda, Wd, c.Cin, 0L,
        v_t, c.O, (long)N_*c.O, c.Cin, nullptr, 0L);
    } else {
      k_gemm_nt<0><<<dim3(N_/BM, c.O/BN, B_), dim3(256), 0, stream>>>(
        c.Xin, c.lda, (long)N_*c.lda, Wa, c.Cin, 0L,
        u_t, c.O, (long)N_*c.O, c.Cin, nullptr, 0L);
      k_gemm_nt<0><<<dim3(N_/BM, c.O/BN, B_), dim3(256), 0, stream>>>(
        c.Xin, c.lda, (long)N_*c.lda, Wd, c.Cin, 0L,
        v_t, c.O, (long)N_*c.O, c.Cin, nullptr, 0L);
    }
    hipMemsetAsync(ssum, 0, 512*sizeof(float), stream);
    hipMemsetAsync(ssq, 0, 512*sizeof(float), stream);
    k_edge_assemble<<<dim3(B_*(N_/64)), dim3(256), 0, stream>>>(u_t, v_t, idxp, xc, c.O, c.c0, ssum, ssq);
    k_bn_finalize<<<dim3(1), dim3(512), 0, stream>>>(ssum, ssq, c.g, c.bb, sc, sh, c.O, (double)B_*N_*K_);
    k_bn_apply<<<dim3((B_*N_*c.O)/256), dim3(256), 0, stream>>>(xc, c.O, c.c0, sc, sh);
  }

  // head: h5 = xc . W5^T, BN stats, finalize, pool
  k_gemm128<0><<<dim3(N_/GBM, 512/GBN, B_), dim3(256), 0, stream>>>(
    xc, 512, (long)N_*512, W5, 512, 0L, h5, 512, (long)N_*512, 512, nullptr, 0L);
  hipMemsetAsync(ssum, 0, 512*sizeof(float), stream);
  hipMemsetAsync(ssq, 0, 512*sizeof(float), stream);
  k_h5_stats<<<dim3(B_*(N_/64)), dim3(512), 0, stream>>>(h5, ssum, ssq);
  k_bn_finalize<<<dim3(1), dim3(512), 0, stream>>>(ssum, ssq, g5, b5, sc, sh, 512, (double)B_*N_);
  k_final_partial<<<dim3(B_*16), dim3(512), 0, stream>>>(h5, sc, sh, pmax, psum);
  k_final_combine<<<dim3(B_), dim3(512), 0, stream>>>(pmax, psum, out);
}